// Round 9
// baseline (244.252 us; speedup 1.0000x reference)
//
#include <hip/hip_runtime.h>
#include <hip/hip_bf16.h>
#include <math.h>

typedef __attribute__((ext_vector_type(8))) _Float16 half8;
typedef __attribute__((ext_vector_type(2))) _Float16 half2v;
typedef __attribute__((ext_vector_type(4))) float f32x4;
typedef __attribute__((ext_vector_type(4))) unsigned int u32x4;

#define NPT 1024
#define D   128

__device__ __forceinline__ unsigned int absdiff_pk(unsigned int a, unsigned int b) {
  half2v d = __builtin_bit_cast(half2v, a) - __builtin_bit_cast(half2v, b);
  return __builtin_bit_cast(unsigned int, d) & 0x7FFF7FFFu;
}
__device__ __forceinline__ unsigned int pk_max(unsigned int a, unsigned int b) {
  unsigned int r;
  asm("v_pk_max_f16 %0, %1, %2" : "=v"(r) : "v"(a), "v"(b));
  return r;
}
__device__ __forceinline__ unsigned int pkrtz(float lo, float hi) {
  return __builtin_bit_cast(unsigned int, __builtin_amdgcn_cvt_pkrtz(lo, hi));
}
__device__ __forceinline__ float fdot2(unsigned int a, unsigned int b, float c) {
  return __builtin_amdgcn_fdot2(__builtin_bit_cast(half2v, a),
                                __builtin_bit_cast(half2v, b), c, false);
}

// ---------------- kernel 1: prep ----------------
// xsw: swizzled f16 x: row i base i*256B, elem k at ((2k)^((i&7)<<4))
// w1p: fragment-ordered f16 W1: w1p[((k>>3)*128+hid)*8 + (k&7)] = W1[k][hid]
// xwghT: f16 [128 t][1024 i] transpose of x@Wg
__global__ __launch_bounds__(128) void k_prep(const float* __restrict__ x,
                                              const float* __restrict__ W1,
                                              const float* __restrict__ Wg,
                                              float* __restrict__ deg,
                                              unsigned short* __restrict__ xsw,
                                              unsigned short* __restrict__ w1p,
                                              unsigned short* __restrict__ xwghT) {
  __shared__ float xi[D];
  const int i = blockIdx.x;
  const int t = threadIdx.x;
  const float xv = x[i * D + t];
  xi[t] = xv;
  if (t == 0) deg[i] = 0.f;
  const _Float16 hv = (_Float16)xv;
  const int byte = i * 256 + ((2 * t) ^ ((i & 7) << 4));
  *(unsigned short*)((unsigned char*)xsw + byte) =
      __builtin_bit_cast(unsigned short, hv);
  if (i < 128) {  // t = k, i = hid
    const _Float16 wv = (_Float16)W1[t * 128 + i];
    w1p[((t >> 3) * 128 + i) * 8 + (t & 7)] = __builtin_bit_cast(unsigned short, wv);
  }
  __syncthreads();
  float acc = 0.f;
#pragma unroll 8
  for (int k = 0; k < D; ++k) acc += xi[k] * Wg[k * D + t];
  const _Float16 av = (_Float16)acc;
  xwghT[t * NPT + i] = __builtin_bit_cast(unsigned short, av);
}

// ---------------- kernel 2: adjacency, f16 MFMA, software-pipelined epilogue ----
// 2048 blocks x 64 thr (1 wave). Wave = 1 i-row x 512 j (32 groups of 16).
// Full 128-hid W1 in 128 regs. Group g's dot/sigmoid runs under group g+1's MFMAs.
__global__ __launch_bounds__(64, 2) void k_adj(const unsigned short* __restrict__ xsw,
                                               const unsigned short* __restrict__ w1p,
                                               const float* __restrict__ b1,
                                               const float* __restrict__ W2,
                                               const float* __restrict__ b2,
                                               float* __restrict__ adj,
                                               float* __restrict__ deg) {
  const int lane = threadIdx.x & 63;
  const int l15  = lane & 15;
  const int g    = lane >> 4;
  const int i  = blockIdx.x >> 1;
  const int jq = blockIdx.x & 1;

  // W1 -> regs: A[m=hid][k], hid = ht*16+l15, k = ks*32+g*8+e
  half8 w1f[4][8];
#pragma unroll
  for (int ks = 0; ks < 4; ++ks)
#pragma unroll
    for (int ht = 0; ht < 8; ++ht)
      w1f[ks][ht] = *(const half8*)(w1p + ((ks * 4 + g) * 128 + ht * 16 + l15) * 8);

  // relu(a+b1)*w2 = max(a,-b1)*w2 + b1*w2
  unsigned int nb1pk[8][2], w2pk[8][2];
  float c0 = 0.f;
#pragma unroll
  for (int ht = 0; ht < 8; ++ht) {
    const f32x4 bv = *(const f32x4*)&b1[ht * 16 + g * 4];
    const f32x4 wv = *(const f32x4*)&W2[ht * 16 + g * 4];
    c0 += bv[0] * wv[0] + bv[1] * wv[1] + bv[2] * wv[2] + bv[3] * wv[3];
    nb1pk[ht][0] = pkrtz(-bv[0], -bv[1]);
    nb1pk[ht][1] = pkrtz(-bv[2], -bv[3]);
    w2pk[ht][0] = pkrtz(wv[0], wv[1]);
    w2pk[ht][1] = pkrtz(wv[2], wv[3]);
  }
  c0 += __shfl_xor(c0, 16);
  c0 += __shfl_xor(c0, 32);
  const float B2 = b2[0] + c0;

  // xi fragments (broadcast row i)
  const unsigned char* xsb = (const unsigned char*)xsw;
  const unsigned char* xrow = xsb + i * 256;
  const int sxI = (i & 7) << 4;
  u32x4 xiu[4];
#pragma unroll
  for (int ks = 0; ks < 4; ++ks)
    xiu[ks] = *(const u32x4*)(xrow + ((ks * 64 + g * 16) ^ sxI));

  const int sxJ = (l15 & 7) << 4;
  const unsigned char* jrow = xsb + (jq * 512 + l15) * 256;
  const int kb0 = (0 * 64 + g * 16) ^ sxJ;
  const int kb1 = (1 * 64 + g * 16) ^ sxJ;
  const int kb2 = (2 * 64 + g * 16) ^ sxJ;
  const int kb3 = (3 * 64 + g * 16) ^ sxJ;

  f32x4 acc[8];
  unsigned int h[16];
  float degacc = 0.f;

  // loads + absdiff + 32 MFMA for group grp -> acc
  auto phase = [&](int grp) {
    const unsigned char* p = jrow + grp * 4096;
    const u32x4 jr0 = *(const u32x4*)(p + kb0);
    const u32x4 jr1 = *(const u32x4*)(p + kb1);
    const u32x4 jr2 = *(const u32x4*)(p + kb2);
    const u32x4 jr3 = *(const u32x4*)(p + kb3);
#pragma unroll
    for (int ht = 0; ht < 8; ++ht) acc[ht] = f32x4{0.f, 0.f, 0.f, 0.f};
    {
      u32x4 afu;
#pragma unroll
      for (int p4 = 0; p4 < 4; ++p4) afu[p4] = absdiff_pk(jr0[p4], xiu[0][p4]);
      const half8 af = __builtin_bit_cast(half8, afu);
#pragma unroll
      for (int ht = 0; ht < 8; ++ht)
        acc[ht] = __builtin_amdgcn_mfma_f32_16x16x32_f16(w1f[0][ht], af, acc[ht], 0, 0, 0);
    }
    {
      u32x4 afu;
#pragma unroll
      for (int p4 = 0; p4 < 4; ++p4) afu[p4] = absdiff_pk(jr1[p4], xiu[1][p4]);
      const half8 af = __builtin_bit_cast(half8, afu);
#pragma unroll
      for (int ht = 0; ht < 8; ++ht)
        acc[ht] = __builtin_amdgcn_mfma_f32_16x16x32_f16(w1f[1][ht], af, acc[ht], 0, 0, 0);
    }
    {
      u32x4 afu;
#pragma unroll
      for (int p4 = 0; p4 < 4; ++p4) afu[p4] = absdiff_pk(jr2[p4], xiu[2][p4]);
      const half8 af = __builtin_bit_cast(half8, afu);
#pragma unroll
      for (int ht = 0; ht < 8; ++ht)
        acc[ht] = __builtin_amdgcn_mfma_f32_16x16x32_f16(w1f[2][ht], af, acc[ht], 0, 0, 0);
    }
    {
      u32x4 afu;
#pragma unroll
      for (int p4 = 0; p4 < 4; ++p4) afu[p4] = absdiff_pk(jr3[p4], xiu[3][p4]);
      const half8 af = __builtin_bit_cast(half8, afu);
#pragma unroll
      for (int ht = 0; ht < 8; ++ht)
        acc[ht] = __builtin_amdgcn_mfma_f32_16x16x32_f16(w1f[3][ht], af, acc[ht], 0, 0, 0);
    }
  };

  // acc -> packed f16 h (the only wait on MFMA results)
  auto pack = [&]() {
#pragma unroll
    for (int ht = 0; ht < 8; ++ht) {
      h[2 * ht + 0] = pk_max(pkrtz(acc[ht][0], acc[ht][1]), nb1pk[ht][0]);
      h[2 * ht + 1] = pk_max(pkrtz(acc[ht][2], acc[ht][3]), nb1pk[ht][1]);
    }
  };

  // finish previous group's score from h (independent of in-flight MFMAs)
  auto dotf = [&]() -> float {
    float sA = 0.f, sB = 0.f, sC = 0.f, sD = 0.f;
#pragma unroll
    for (int ht = 0; ht < 8; ht += 2) {
      sA = fdot2(h[2 * ht + 0], w2pk[ht][0], sA);
      sB = fdot2(h[2 * ht + 1], w2pk[ht][1], sB);
      sC = fdot2(h[2 * ht + 2], w2pk[ht + 1][0], sC);
      sD = fdot2(h[2 * ht + 3], w2pk[ht + 1][1], sD);
    }
    float s = (sA + sB) + (sC + sD);
    s += __shfl_xor(s, 16);
    s += __shfl_xor(s, 32);
    return 1.f / (1.f + __expf(-(s + B2)));
  };

  phase(0);
  pack();
#pragma unroll 1
  for (int b4 = 0; b4 < 8; ++b4) {
    const int gb = b4 * 4;
    float s0, s1, s2, s3;
    phase(gb + 1); s0 = dotf(); pack();
    phase(gb + 2); s1 = dotf(); pack();
    phase(gb + 3); s2 = dotf(); pack();
    if (b4 < 7) { phase(gb + 4); s3 = dotf(); pack(); }
    else        { s3 = dotf(); }
    const float v = (g == 0) ? s0 : (g == 1) ? s1 : (g == 2) ? s2 : s3;
    adj[i * NPT + jq * 512 + b4 * 64 + lane] = v;  // full 256B line
    degacc += (s0 + s1) + (s2 + s3);
  }
  // every j counted 4x (g-replicated) -> *0.25
#pragma unroll
  for (int m = 1; m <= 32; m <<= 1) degacc += __shfl_xor(degacc, m);
  if (lane == 0) atomicAdd(&deg[i], degacc * 0.25f);
}

// ---------------- kernel 3: dinv f16 ----------------
__global__ __launch_bounds__(512) void k_dinv(const float* __restrict__ deg,
                                              unsigned short* __restrict__ dinvh) {
  const int idx = blockIdx.x * 512 + threadIdx.x;
  const _Float16 dh = (_Float16)rsqrtf(deg[idx]);
  dinvh[idx] = __builtin_bit_cast(unsigned short, dh);
}

// ---------------- kernel 4: out-partial via f16 MFMA, D[m=t][n=i], no atomics ----
// out[t][i] = sum_j xwghT[t][j] * (adj[i][j]*dinv_j). grid (64,4) x 128 thr (2 waves).
__global__ __launch_bounds__(128) void k_d1(const float* __restrict__ adj,
                                            const unsigned short* __restrict__ xwghT,
                                            const unsigned short* __restrict__ dinvh,
                                            float* __restrict__ outp) {
  const int tid  = threadIdx.x;
  const int lane = tid & 63;
  const int w    = tid >> 6;
  const int l15  = lane & 15;
  const int g    = lane >> 4;
  const int i0 = blockIdx.x * 16;
  const int t0 = (blockIdx.y * 2 + w) * 16;

  f32x4 acc{0.f, 0.f, 0.f, 0.f};
#pragma unroll 2
  for (int ch = 0; ch < 32; ++ch) {
    const int kofs = ch * 32 + g * 8;
    const half8 af = *(const half8*)(xwghT + (t0 + l15) * NPT + kofs);
    const f32x4 av0 = *(const f32x4*)&adj[(i0 + l15) * NPT + kofs];
    const f32x4 av1 = *(const f32x4*)&adj[(i0 + l15) * NPT + kofs + 4];
    const half2v* dq = (const half2v*)(dinvh + kofs);
    u32x4 bu;
    bu[0] = __builtin_bit_cast(unsigned int,
        half2v(__builtin_bit_cast(half2v, pkrtz(av0[0], av0[1])) * dq[0]));
    bu[1] = __builtin_bit_cast(unsigned int,
        half2v(__builtin_bit_cast(half2v, pkrtz(av0[2], av0[3])) * dq[1]));
    bu[2] = __builtin_bit_cast(unsigned int,
        half2v(__builtin_bit_cast(half2v, pkrtz(av1[0], av1[1])) * dq[2]));
    bu[3] = __builtin_bit_cast(unsigned int,
        half2v(__builtin_bit_cast(half2v, pkrtz(av1[2], av1[3])) * dq[3]));
    acc = __builtin_amdgcn_mfma_f32_16x16x32_f16(__builtin_bit_cast(half8, af),
                                                 __builtin_bit_cast(half8, bu), acc, 0, 0, 0);
  }
  // D: col(lane&15)=i-local, row=(g*4+r)=t-local
  *(f32x4*)&outp[(i0 + l15) * D + t0 + g * 4] = acc;
}

// ---------------- kernel 5: out = leaky(rsqrt(deg_i) * partial + bg) --------
__global__ void k_d2(float* __restrict__ outp, const float* __restrict__ deg,
                     const float* __restrict__ bg) {
  const int idx = blockIdx.x * 256 + threadIdx.x;
  const int i = idx >> 7, t = idx & 127;
  const float v = outp[idx] * rsqrtf(deg[i]) + bg[t];
  outp[idx] = v > 0.f ? v : 0.2f * v;
}

extern "C" void kernel_launch(void* const* d_in, const int* in_sizes, int n_in,
                              void* d_out, int out_size, void* d_ws, size_t ws_size,
                              hipStream_t stream) {
  const float* x  = (const float*)d_in[0];
  const float* W1 = (const float*)d_in[1];
  const float* b1 = (const float*)d_in[2];
  const float* W2 = (const float*)d_in[3];
  const float* b2 = (const float*)d_in[4];
  const float* Wg = (const float*)d_in[5];
  const float* bg = (const float*)d_in[6];

  float* outp = (float*)d_out;                  // [1024*128]
  float* adj  = outp + NPT * D;                 // [1024*1024]
  unsigned char* ws = (unsigned char*)d_ws;
  float* deg            = (float*)ws;                               // 4KB @0
  unsigned short* xsw   = (unsigned short*)(ws + 4096);             // 256KB
  unsigned short* w1p   = (unsigned short*)(ws + 4096 + 262144);    // 32KB
  unsigned short* xwghT = (unsigned short*)(ws + 4096 + 262144 + 32768);  // 256KB
  unsigned short* dinvh = (unsigned short*)(ws + 4096 + 262144 + 32768 + 262144); // 2KB

  k_prep<<<NPT, 128, 0, stream>>>(x, W1, Wg, deg, xsw, w1p, xwghT);
  k_adj<<<2048, 64, 0, stream>>>(xsw, w1p, b1, W2, b2, adj, deg);
  k_dinv<<<2, 512, 0, stream>>>(deg, dinvh);
  k_d1<<<dim3(64, 4), 128, 0, stream>>>(adj, xwghT, dinvh, outp);
  k_d2<<<512, 256, 0, stream>>>(outp, deg, bg);
}

// Round 10
// 62.963 us; speedup vs baseline: 3.8793x; 3.8793x over previous
//
#include <hip/hip_runtime.h>
#include <hip/hip_bf16.h>
#include <math.h>

typedef __attribute__((ext_vector_type(8))) _Float16 half8;
typedef __attribute__((ext_vector_type(2))) _Float16 half2v;
typedef __attribute__((ext_vector_type(4))) float f32x4;
typedef __attribute__((ext_vector_type(4))) unsigned int u32x4;

#define NPT 1024
#define D   128

__device__ __forceinline__ unsigned int absdiff_pk(unsigned int a, unsigned int b) {
  half2v d = __builtin_bit_cast(half2v, a) - __builtin_bit_cast(half2v, b);
  return __builtin_bit_cast(unsigned int, d) & 0x7FFF7FFFu;
}
__device__ __forceinline__ unsigned int pk_max(unsigned int a, unsigned int b) {
  unsigned int r;
  asm("v_pk_max_f16 %0, %1, %2" : "=v"(r) : "v"(a), "v"(b));
  return r;
}
__device__ __forceinline__ unsigned int pkrtz(float lo, float hi) {
  return __builtin_bit_cast(unsigned int, __builtin_amdgcn_cvt_pkrtz(lo, hi));
}
__device__ __forceinline__ float fdot2(unsigned int a, unsigned int b, float c) {
  return __builtin_amdgcn_fdot2(__builtin_bit_cast(half2v, a),
                                __builtin_bit_cast(half2v, b), c, false);
}

// ---------------- kernel 1: prep ----------------
// xsw: swizzled f16 x: row i base i*256B, elem k at ((2k)^((i&7)<<4))
// w1p: fragment-ordered f16 W1: w1p[((k>>3)*128+hid)*8 + (k&7)] = W1[k][hid]
// xwghT: f16 [128 t][1024 i] transpose of x@Wg
__global__ __launch_bounds__(128) void k_prep(const float* __restrict__ x,
                                              const float* __restrict__ W1,
                                              const float* __restrict__ Wg,
                                              float* __restrict__ deg,
                                              unsigned short* __restrict__ xsw,
                                              unsigned short* __restrict__ w1p,
                                              unsigned short* __restrict__ xwghT) {
  __shared__ float xi[D];
  const int i = blockIdx.x;
  const int t = threadIdx.x;
  const float xv = x[i * D + t];
  xi[t] = xv;
  if (t == 0) deg[i] = 0.f;
  const _Float16 hv = (_Float16)xv;
  const int byte = i * 256 + ((2 * t) ^ ((i & 7) << 4));
  *(unsigned short*)((unsigned char*)xsw + byte) =
      __builtin_bit_cast(unsigned short, hv);
  if (i < 128) {  // t = k, i = hid
    const _Float16 wv = (_Float16)W1[t * 128 + i];
    w1p[((t >> 3) * 128 + i) * 8 + (t & 7)] = __builtin_bit_cast(unsigned short, wv);
  }
  __syncthreads();
  float acc = 0.f;
#pragma unroll 8
  for (int k = 0; k < D; ++k) acc += xi[k] * Wg[k * D + t];
  const _Float16 av = (_Float16)acc;
  xwghT[t * NPT + i] = __builtin_bit_cast(unsigned short, av);
}

// ---------------- kernel 2: adjacency, f16 MFMA, staggered waves ----------------
// grid (256,2) x 256 thr. Wave = 1 i-row x 512 j (32 groups of 16).
// Full 128-hid W1 in 128 regs (AGPR side). Per-wave group-order rotation
// rot=(2w+jq)*4 anti-phases the 2 co-resident waves/SIMD (convoy breaker).
__global__ __launch_bounds__(256, 2) void k_adj(const unsigned short* __restrict__ xsw,
                                                const unsigned short* __restrict__ w1p,
                                                const float* __restrict__ b1,
                                                const float* __restrict__ W2,
                                                const float* __restrict__ b2,
                                                float* __restrict__ adj,
                                                float* __restrict__ deg) {
  const int tid  = threadIdx.x;
  const int lane = tid & 63;
  const int w    = tid >> 6;   // 0..3
  const int l15  = lane & 15;
  const int g    = lane >> 4;  // 0..3
  const int i  = blockIdx.x * 4 + w;
  const int jq = blockIdx.y;   // 0..1
  const int rot = ((w * 2 + jq) & 7) * 4;  // 0,4,...,28

  // W1 -> regs: A[m=hid][k], hid = ht*16+l15, k = ks*32+g*8+e
  half8 w1f[4][8];
#pragma unroll
  for (int ks = 0; ks < 4; ++ks)
#pragma unroll
    for (int ht = 0; ht < 8; ++ht)
      w1f[ks][ht] = *(const half8*)(w1p + ((ks * 4 + g) * 128 + ht * 16 + l15) * 8);

  // relu(a+b1)*w2 = max(a,-b1)*w2 + b1*w2
  unsigned int nb1pk[8][2], w2pk[8][2];
  float c0 = 0.f;
#pragma unroll
  for (int ht = 0; ht < 8; ++ht) {
    const f32x4 bv = *(const f32x4*)&b1[ht * 16 + g * 4];
    const f32x4 wv = *(const f32x4*)&W2[ht * 16 + g * 4];
    c0 += bv[0] * wv[0] + bv[1] * wv[1] + bv[2] * wv[2] + bv[3] * wv[3];
    nb1pk[ht][0] = pkrtz(-bv[0], -bv[1]);
    nb1pk[ht][1] = pkrtz(-bv[2], -bv[3]);
    w2pk[ht][0] = pkrtz(wv[0], wv[1]);
    w2pk[ht][1] = pkrtz(wv[2], wv[3]);
  }
  c0 += __shfl_xor(c0, 16);
  c0 += __shfl_xor(c0, 32);
  const float B2 = b2[0] + c0;

  // xi fragments (broadcast row i)
  const unsigned char* xsb = (const unsigned char*)xsw;
  const unsigned char* xrow = xsb + i * 256;
  const int sxI = (i & 7) << 4;
  u32x4 xiu[4];
#pragma unroll
  for (int ks = 0; ks < 4; ++ks)
    xiu[ks] = *(const u32x4*)(xrow + ((ks * 64 + g * 16) ^ sxI));

  const int sxJ = (l15 & 7) << 4;
  const unsigned char* jrow = xsb + (jq * 512 + l15) * 256;
  const int kb0 = (0 * 64 + g * 16) ^ sxJ;
  const int kb1 = (1 * 64 + g * 16) ^ sxJ;
  const int kb2 = (2 * 64 + g * 16) ^ sxJ;
  const int kb3 = (3 * 64 + g * 16) ^ sxJ;

  // prime group rot
  {
    const unsigned char* p = jrow + rot * 4096;
    (void)p;
  }
  u32x4 jr0 = *(const u32x4*)(jrow + rot * 4096 + kb0);
  u32x4 jr1 = *(const u32x4*)(jrow + rot * 4096 + kb1);
  u32x4 jr2 = *(const u32x4*)(jrow + rot * 4096 + kb2);
  u32x4 jr3 = *(const u32x4*)(jrow + rot * 4096 + kb3);

  float degacc = 0.f;

#pragma unroll 1
  for (int b4 = 0; b4 < 8; ++b4) {
    float sv[4];
#pragma unroll
    for (int q = 0; q < 4; ++q) {
      const int cnext = b4 * 4 + q + 1;              // logical next
      const int gnext = (cnext + rot) & 31;          // actual next group
      const unsigned char* nrow = jrow + gnext * 4096;

      f32x4 acc[8];
#pragma unroll
      for (int ht = 0; ht < 8; ++ht) acc[ht] = f32x4{0.f, 0.f, 0.f, 0.f};

      __builtin_amdgcn_s_setprio(1);
      {
        u32x4 afu;
#pragma unroll
        for (int p4 = 0; p4 < 4; ++p4) afu[p4] = absdiff_pk(jr0[p4], xiu[0][p4]);
        if (cnext < 32) jr0 = *(const u32x4*)(nrow + kb0);
        const half8 af = __builtin_bit_cast(half8, afu);
#pragma unroll
        for (int ht = 0; ht < 8; ++ht)
          acc[ht] = __builtin_amdgcn_mfma_f32_16x16x32_f16(w1f[0][ht], af, acc[ht], 0, 0, 0);
      }
      {
        u32x4 afu;
#pragma unroll
        for (int p4 = 0; p4 < 4; ++p4) afu[p4] = absdiff_pk(jr1[p4], xiu[1][p4]);
        if (cnext < 32) jr1 = *(const u32x4*)(nrow + kb1);
        const half8 af = __builtin_bit_cast(half8, afu);
#pragma unroll
        for (int ht = 0; ht < 8; ++ht)
          acc[ht] = __builtin_amdgcn_mfma_f32_16x16x32_f16(w1f[1][ht], af, acc[ht], 0, 0, 0);
      }
      {
        u32x4 afu;
#pragma unroll
        for (int p4 = 0; p4 < 4; ++p4) afu[p4] = absdiff_pk(jr2[p4], xiu[2][p4]);
        if (cnext < 32) jr2 = *(const u32x4*)(nrow + kb2);
        const half8 af = __builtin_bit_cast(half8, afu);
#pragma unroll
        for (int ht = 0; ht < 8; ++ht)
          acc[ht] = __builtin_amdgcn_mfma_f32_16x16x32_f16(w1f[2][ht], af, acc[ht], 0, 0, 0);
      }
      {
        u32x4 afu;
#pragma unroll
        for (int p4 = 0; p4 < 4; ++p4) afu[p4] = absdiff_pk(jr3[p4], xiu[3][p4]);
        if (cnext < 32) jr3 = *(const u32x4*)(nrow + kb3);
        const half8 af = __builtin_bit_cast(half8, afu);
#pragma unroll
        for (int ht = 0; ht < 8; ++ht)
          acc[ht] = __builtin_amdgcn_mfma_f32_16x16x32_f16(w1f[3][ht], af, acc[ht], 0, 0, 0);
      }
      __builtin_amdgcn_s_setprio(0);

      // dot: pkrtz+max -> 4 parallel fdot2 chains -> cross-lane reduce
      float sA = 0.f, sB = 0.f, sC = 0.f, sD = 0.f;
#pragma unroll
      for (int ht = 0; ht < 8; ht += 2) {
        unsigned int h0a = pk_max(pkrtz(acc[ht][0], acc[ht][1]), nb1pk[ht][0]);
        unsigned int h0b = pk_max(pkrtz(acc[ht][2], acc[ht][3]), nb1pk[ht][1]);
        unsigned int h1a = pk_max(pkrtz(acc[ht + 1][0], acc[ht + 1][1]), nb1pk[ht + 1][0]);
        unsigned int h1b = pk_max(pkrtz(acc[ht + 1][2], acc[ht + 1][3]), nb1pk[ht + 1][1]);
        sA = fdot2(h0a, w2pk[ht][0], sA);
        sB = fdot2(h0b, w2pk[ht][1], sB);
        sC = fdot2(h1a, w2pk[ht + 1][0], sC);
        sD = fdot2(h1b, w2pk[ht + 1][1], sD);
      }
      float s = (sA + sB) + (sC + sD);
      s += __shfl_xor(s, 16);
      s += __shfl_xor(s, 32);
      sv[q] = 1.f / (1.f + __expf(-(s + B2)));
    }
    // batched store: 4 groups = 64 contiguous j (rot is mult of 4, no wrap)
    const int gbase = (b4 * 4 + rot) & 31;
    const float v = (g == 0) ? sv[0] : (g == 1) ? sv[1] : (g == 2) ? sv[2] : sv[3];
    adj[i * NPT + jq * 512 + gbase * 16 + lane] = v;
    degacc += (sv[0] + sv[1]) + (sv[2] + sv[3]);
  }
  // each j's sig counted once per g (4x) -> reduce over 64 lanes, *0.25
#pragma unroll
  for (int m = 1; m <= 32; m <<= 1) degacc += __shfl_xor(degacc, m);
  if (lane == 0) atomicAdd(&deg[i], degacc * 0.25f);
}

// ---------------- kernel 3: fused d1 (dinv-LDS prologue, MFMA, leaky epilogue) ----
// out[i][t] = leaky( dinv_i * sum_j xwghT[t][j]*(adj[i][j]*dinv_j) + bg[t] )
// grid (64,4) x 128 thr (2 waves). Wave owns one (16i x 16t) tile, loops all j.
__global__ __launch_bounds__(128) void k_d1(const float* __restrict__ adj,
                                            const unsigned short* __restrict__ xwghT,
                                            const float* __restrict__ deg,
                                            const float* __restrict__ bg,
                                            float* __restrict__ outp) {
  __shared__ unsigned short dvh[NPT];
  const int tid  = threadIdx.x;
  const int lane = tid & 63;
  const int w    = tid >> 6;
  const int l15  = lane & 15;
  const int g    = lane >> 4;
  const int i0 = blockIdx.x * 16;
  const int t0 = (blockIdx.y * 2 + w) * 16;

#pragma unroll
  for (int it = 0; it < 8; ++it) {
    const int idx = it * 128 + tid;
    const _Float16 dh = (_Float16)rsqrtf(deg[idx]);
    dvh[idx] = __builtin_bit_cast(unsigned short, dh);
  }
  __syncthreads();

  f32x4 acc{0.f, 0.f, 0.f, 0.f};
#pragma unroll 2
  for (int ch = 0; ch < 32; ++ch) {
    const int kofs = ch * 32 + g * 8;
    const half8 af = *(const half8*)(xwghT + (t0 + l15) * NPT + kofs);
    const f32x4 av0 = *(const f32x4*)&adj[(i0 + l15) * NPT + kofs];
    const f32x4 av1 = *(const f32x4*)&adj[(i0 + l15) * NPT + kofs + 4];
    const half2v* dq = (const half2v*)(dvh + kofs);
    u32x4 bu;
    bu[0] = __builtin_bit_cast(unsigned int,
        half2v(__builtin_bit_cast(half2v, pkrtz(av0[0], av0[1])) * dq[0]));
    bu[1] = __builtin_bit_cast(unsigned int,
        half2v(__builtin_bit_cast(half2v, pkrtz(av0[2], av0[3])) * dq[1]));
    bu[2] = __builtin_bit_cast(unsigned int,
        half2v(__builtin_bit_cast(half2v, pkrtz(av1[0], av1[1])) * dq[2]));
    bu[3] = __builtin_bit_cast(unsigned int,
        half2v(__builtin_bit_cast(half2v, pkrtz(av1[2], av1[3])) * dq[3]));
    acc = __builtin_amdgcn_mfma_f32_16x16x32_f16(__builtin_bit_cast(half8, af),
                                                 __builtin_bit_cast(half8, bu), acc, 0, 0, 0);
  }
  // D: col(l15)=i-local, row=(g*4+r)=t-local. Fused k_d2 epilogue.
  const float di = rsqrtf(deg[i0 + l15]);
  const f32x4 bgv = *(const f32x4*)&bg[t0 + g * 4];
  f32x4 o;
#pragma unroll
  for (int r = 0; r < 4; ++r) {
    const float v = acc[r] * di + bgv[r];
    o[r] = v > 0.f ? v : 0.2f * v;
  }
  *(f32x4*)&outp[(i0 + l15) * D + t0 + g * 4] = o;
}

extern "C" void kernel_launch(void* const* d_in, const int* in_sizes, int n_in,
                              void* d_out, int out_size, void* d_ws, size_t ws_size,
                              hipStream_t stream) {
  const float* x  = (const float*)d_in[0];
  const float* W1 = (const float*)d_in[1];
  const float* b1 = (const float*)d_in[2];
  const float* W2 = (const float*)d_in[3];
  const float* b2 = (const float*)d_in[4];
  const float* Wg = (const float*)d_in[5];
  const float* bg = (const float*)d_in[6];

  float* outp = (float*)d_out;                  // [1024*128]
  float* adj  = outp + NPT * D;                 // [1024*1024]
  unsigned char* ws = (unsigned char*)d_ws;
  float* deg            = (float*)ws;                               // 4KB @0
  unsigned short* xsw   = (unsigned short*)(ws + 4096);             // 256KB
  unsigned short* w1p   = (unsigned short*)(ws + 4096 + 262144);    // 32KB
  unsigned short* xwghT = (unsigned short*)(ws + 4096 + 262144 + 32768);  // 256KB

  k_prep<<<NPT, 128, 0, stream>>>(x, W1, Wg, deg, xsw, w1p, xwghT);
  k_adj<<<dim3(256, 2), 256, 0, stream>>>(xsw, w1p, b1, W2, b2, adj, deg);
  k_d1<<<dim3(64, 4), 128, 0, stream>>>(adj, xwghT, deg, bg, outp);
}